// Round 7
// baseline (113.910 us; speedup 1.0000x reference)
//
#include <hip/hip_runtime.h>
#include <stdint.h>

#define NB 8
#define NN 1024
#define NF 64
#define NT 12
#define NK 3
#define NO 64
#define NQ 768      // O*T
#define KKC 3072    // NK*NN contraction

typedef __attribute__((ext_vector_type(8))) short bf16x8;
typedef __attribute__((ext_vector_type(4))) float f32x4;

typedef const unsigned int __attribute__((address_space(1)))* gas1_t;
typedef unsigned int __attribute__((address_space(3)))* las3_t;

__device__ __forceinline__ void gload_lds16(const void* g, void* l) {
  __builtin_amdgcn_global_load_lds((gas1_t)g, (las3_t)l, 16, 0, 0);
}

__device__ __forceinline__ unsigned short f2bf(float f) {
  union { float f; unsigned int u; } v; v.f = f;
  unsigned int u = v.u;
  unsigned int r = (u + 0x7FFFu + ((u >> 16) & 1u)) >> 16;
  return (unsigned short)r;
}

// ---------------------------------------------------------------------------
// K0: thetaT[k][o][f] = bf16(theta[k][f][o])
// ---------------------------------------------------------------------------
__global__ void k0_thetaT(const float* __restrict__ theta, unsigned short* __restrict__ thT) {
  int i = blockIdx.x * 256 + threadIdx.x;
  if (i >= NK * NO * NF) return;
  int f = i & 63, o = (i >> 6) & 63, k = i >> 12;
  thT[i] = f2bf(theta[(k * NF + f) * NO + o]);
}

// ---------------------------------------------------------------------------
// K1: A2[b][n][k*1024+m] = bf16(cheb[k][m][n]*att[b][m][n])
// Restructured: grid (n0,m0) = 256 blocks; cheb tiles staged ONCE (3 k's),
// loop b inside (att tile per b). Cheb HBM traffic 100 MB -> 12.6 MB.
// ---------------------------------------------------------------------------
__global__ __launch_bounds__(256) void k1_A2(const float* __restrict__ cheb,
                                             const float* __restrict__ att,
                                             unsigned short* __restrict__ A2) {
  __shared__ float att_s[64][65];
  __shared__ float cheb_s[3][64][65];
  const int n0 = blockIdx.x * 64;
  const int m0 = blockIdx.y * 64;
  const int tid = threadIdx.x;
  const int r4 = tid >> 4;
  const int c  = tid & 15;

#pragma unroll
  for (int k = 0; k < NK; ++k)
#pragma unroll
    for (int p = 0; p < 4; ++p) {
      int r = r4 + p * 16;
      const float4 v = *(const float4*)(cheb + ((size_t)(k * NN + m0 + r)) * NN + n0 + c * 4);
      cheb_s[k][r][c * 4 + 0] = v.x; cheb_s[k][r][c * 4 + 1] = v.y;
      cheb_s[k][r][c * 4 + 2] = v.z; cheb_s[k][r][c * 4 + 3] = v.w;
    }

  for (int b = 0; b < NB; ++b) {
    __syncthreads();   // cheb ready (b=0) / previous b's reads of att_s done
#pragma unroll
    for (int p = 0; p < 4; ++p) {
      int r = r4 + p * 16;
      const float4 v = *(const float4*)(att + ((size_t)(b * NN + m0 + r)) * NN + n0 + c * 4);
      att_s[r][c * 4 + 0] = v.x; att_s[r][c * 4 + 1] = v.y;
      att_s[r][c * 4 + 2] = v.z; att_s[r][c * 4 + 3] = v.w;
    }
    __syncthreads();   // att ready
    for (int k = 0; k < NK; ++k) {
#pragma unroll
      for (int p = 0; p < 8; ++p) {
        int e  = p * 256 + tid;
        int jn = e >> 5;
        int q  = e & 31;
        float f0 = att_s[2 * q][jn]     * cheb_s[k][2 * q][jn];
        float f1 = att_s[2 * q + 1][jn] * cheb_s[k][2 * q + 1][jn];
        unsigned int pk = (unsigned int)f2bf(f0) | ((unsigned int)f2bf(f1) << 16);
        size_t el = ((size_t)(b * NN + n0 + jn)) * KKC + k * NN + m0 + 2 * q;
        *(unsigned int*)(A2 + el) = pk;
      }
    }
  }
}

// ---------------------------------------------------------------------------
// K2: xT[b][t][m][f] = bf16(x[b][m][f][t])  (LDS transpose, contiguous reads)
// ---------------------------------------------------------------------------
__global__ __launch_bounds__(256) void k2_xT(const float* __restrict__ x,
                                             unsigned short* __restrict__ xT) {
  __shared__ unsigned int lds[12][16][32];
  const int m0 = blockIdx.x * 16;
  const int b  = blockIdx.y;
  const int tid = threadIdx.x;
  const float* xb = x + ((size_t)(b * NN + m0)) * (NF * NT);

#pragma unroll
  for (int u0 = 0; u0 < 2; ++u0) {
    const int u  = u0 * 256 + tid;
    const int ml = u >> 5;
    const int fp = u & 31;
    const float* src = xb + ((size_t)ml * NF + fp * 2) * NT;
    float v[24];
#pragma unroll
    for (int i = 0; i < 6; ++i)
      *(float4*)(v + i * 4) = *(const float4*)(src + i * 4);
#pragma unroll
    for (int t = 0; t < 12; ++t) {
      unsigned int pk = (unsigned int)f2bf(v[t]) | ((unsigned int)f2bf(v[t + 12]) << 16);
      lds[t][ml][fp] = pk;
    }
  }
  __syncthreads();

#pragma unroll
  for (int it = 0; it < 12; ++it) {
    const int g = it * 256 + tid;
    const int t = g >> 8;
    const int r = g & 255;
    const int m = r >> 4;
    const int f4 = r & 15;
    uint2 u = *(const uint2*)&lds[t][m][2 * f4];
    size_t el = (((size_t)(b * NT + t) * NN) + m0 + m) * NF + f4 * 4;
    *(uint2*)(void*)(xT + el) = u;
  }
}

// ---------------------------------------------------------------------------
// K3: Y2t[b][o*12+t][k*1024+m] = sum_f xT[b][t][m][f] * thT[k][o][f]
// grid (mc=4, t=12, b=8). Stage xT tile in LDS once, reuse across 3 k's.
// ---------------------------------------------------------------------------
__global__ __launch_bounds__(256) void k3_Y(const unsigned short* __restrict__ xT,
                                            const unsigned short* __restrict__ thT,
                                            unsigned short* __restrict__ Y) {
  __shared__ unsigned short Xs[256 * 64];   // 32 KB
  const int mc = blockIdx.x;
  const int t  = blockIdx.y;
  const int b  = blockIdx.z;
  const int tid = threadIdx.x;
  const int w = tid >> 6, l = tid & 63;
  const int lrow = l & 15, lk = l >> 4;

  const unsigned short* xbase = xT + ((size_t)(b * NT + t)) * NN * NF + (size_t)(mc * 256) * NF;

#pragma unroll
  for (int it = 0; it < 8; ++it) {
    const int idx = it * 256 + tid;          // 16B-unit index
    const int r   = idx >> 3;
    const int c16 = (idx & 7) ^ (r & 7);
    gload_lds16(xbase + (size_t)r * NF + c16 * 8, Xs + (size_t)idx * 8);
  }
  __syncthreads();

  bf16x8 af[2][4];
#pragma unroll
  for (int ks = 0; ks < 2; ++ks)
#pragma unroll
    for (int mi = 0; mi < 4; ++mi) {
      const int row = w * 64 + mi * 16 + lrow;
      const int sw = (row * 128 + ks * 64 + lk * 16) ^ ((row & 7) << 4);
      af[ks][mi] = *(const bf16x8*)((const char*)Xs + sw);
    }

  for (int k = 0; k < NK; ++k) {
    const unsigned short* tb = thT + (size_t)k * NO * NF;
    f32x4 acc[4][4] = {};
#pragma unroll
    for (int ks = 0; ks < 2; ++ks) {
      bf16x8 bb[4];
#pragma unroll
      for (int oj = 0; oj < 4; ++oj)
        bb[oj] = *(const bf16x8*)(tb + (size_t)(oj * 16 + lrow) * NF + ks * 32 + lk * 8);
#pragma unroll
      for (int mi = 0; mi < 4; ++mi)
#pragma unroll
        for (int oj = 0; oj < 4; ++oj)
          acc[mi][oj] = __builtin_amdgcn_mfma_f32_16x16x32_bf16(af[ks][mi], bb[oj], acc[mi][oj], 0, 0, 0);
    }
#pragma unroll
    for (int mi = 0; mi < 4; ++mi) {
#pragma unroll
      for (int oj = 0; oj < 4; ++oj) {
        const int o  = oj * 16 + lrow;
        const int mg = mc * 256 + w * 64 + mi * 16 + lk * 4;
        uint2 u;
        u.x = (unsigned int)f2bf(acc[mi][oj][0]) | ((unsigned int)f2bf(acc[mi][oj][1]) << 16);
        u.y = (unsigned int)f2bf(acc[mi][oj][2]) | ((unsigned int)f2bf(acc[mi][oj][3]) << 16);
        size_t el = ((size_t)(b * NQ + o * NT + t)) * KKC + k * NN + mg;
        *(uint2*)(void*)(Y + el) = u;
      }
    }
  }
}

// ---------------------------------------------------------------------------
// K4: out[b][n][q] = relu( A2[b] @ Y[b]^T ), 128x192 tile, BK=64, 512 thr
// (8 waves, 2m x 4q, per-wave 64x48, acc 4x3). Grid 8x4x8 = 256 = 1/CU.
// Staged bytes: 256 x 320 x 3072 x 2 = 503 MB (was 906) -- the round-6
// diagnosis says k4 is L2/L3 staging-BW bound at ~17 TB/s, so bytes is
// the lever. At 1 block/CU the counted-vmcnt dbuf (r5) is now essential:
// STAGE(next) -> vmcnt(5) -> barrier -> COMPUTE(cur) -> barrier.
// XCD-chunk swizzle: 32 blocks (= one b) per XCD.
// ---------------------------------------------------------------------------
__global__ __launch_bounds__(512) void k4_main(const unsigned short* __restrict__ A2,
                                               const unsigned short* __restrict__ Y,
                                               float* __restrict__ out) {
  __shared__ unsigned short Asl[2][128 * 64];   // 16 KB each
  __shared__ unsigned short Bsl[2][192 * 64];   // 24 KB each
  const int tid = threadIdx.x;
  const int w = tid >> 6, l = tid & 63;
  const int lrow = l & 15, lk = l >> 4;
  const int wm = w >> 2, wq = w & 3;

  const int lin = (blockIdx.x & 7) * 32 + (blockIdx.x >> 3);
  const int b   = lin >> 5;
  const int rem = lin & 31;
  const int bn  = rem >> 2;      // 0..7, 128-row n-tile
  const int bq  = rem & 3;       // 0..3, 192-col q-tile

  const unsigned short* Abase = A2 + ((size_t)(b * NN + bn * 128)) * KKC;
  const unsigned short* Bbase = Y  + ((size_t)(b * NQ + bq * 192)) * KKC;

  f32x4 acc[4][3] = {};

  auto STAGE = [&](int buf, int kt) {
    const int kb = kt * 64;
#pragma unroll
    for (int it = 0; it < 2; ++it) {            // A: 1024 units, 2/thread
      const int idx = it * 512 + tid;
      const int r   = idx >> 3;
      const int c16 = (idx & 7) ^ (r & 7);
      gload_lds16(Abase + (size_t)r * KKC + kb + c16 * 8, Asl[buf] + (size_t)idx * 8);
    }
#pragma unroll
    for (int it = 0; it < 3; ++it) {            // B: 1536 units, 3/thread
      const int idx = it * 512 + tid;
      const int r   = idx >> 3;
      const int c16 = (idx & 7) ^ (r & 7);
      gload_lds16(Bbase + (size_t)r * KKC + kb + c16 * 8, Bsl[buf] + (size_t)idx * 8);
    }
  };

  auto COMPUTE = [&](int buf) {
#pragma unroll
    for (int ks = 0; ks < 2; ++ks) {
      bf16x8 af[4], bfr[3];
#pragma unroll
      for (int mi = 0; mi < 4; ++mi) {
        const int row = wm * 64 + mi * 16 + lrow;
        const int sw = (row * 128 + ks * 64 + lk * 16) ^ ((row & 7) << 4);
        af[mi] = *(const bf16x8*)((const char*)Asl[buf] + sw);
      }
#pragma unroll
      for (int nj = 0; nj < 3; ++nj) {
        const int row = wq * 48 + nj * 16 + lrow;
        const int sw = (row * 128 + ks * 64 + lk * 16) ^ ((row & 7) << 4);
        bfr[nj] = *(const bf16x8*)((const char*)Bsl[buf] + sw);
      }
#pragma unroll
      for (int mi = 0; mi < 4; ++mi)
#pragma unroll
        for (int nj = 0; nj < 3; ++nj)
          acc[mi][nj] = __builtin_amdgcn_mfma_f32_16x16x32_bf16(af[mi], bfr[nj], acc[mi][nj], 0, 0, 0);
    }
  };

  STAGE(0, 0);                                  // 5 loads/thread in flight
  for (int kt = 0; kt < KKC / 64; ++kt) {
    const int p = kt & 1;
    if (kt + 1 < KKC / 64) {
      STAGE(p ^ 1, kt + 1);                     // 10 in flight
      asm volatile("s_waitcnt vmcnt(5)" ::: "memory");   // cur tile landed
    } else {
      asm volatile("s_waitcnt vmcnt(0)" ::: "memory");
    }
    __builtin_amdgcn_s_barrier();
    COMPUTE(p);
    __builtin_amdgcn_s_barrier();
  }

  const int nb0 = bn * 128 + wm * 64;
  const int qb0 = bq * 192 + wq * 48;
#pragma unroll
  for (int mi = 0; mi < 4; ++mi) {
#pragma unroll
    for (int nj = 0; nj < 3; ++nj) {
      const int q = qb0 + nj * 16 + lrow;
#pragma unroll
      for (int j = 0; j < 4; ++j) {
        const int n = nb0 + mi * 16 + lk * 4 + j;
        float v = acc[mi][nj][j];
        out[((size_t)(b * NN + n)) * NQ + q] = v > 0.f ? v : 0.f;
      }
    }
  }
}

// ---------------------------------------------------------------------------
extern "C" void kernel_launch(void* const* d_in, const int* in_sizes, int n_in,
                              void* d_out, int out_size, void* d_ws, size_t ws_size,
                              hipStream_t stream) {
  const float* x     = (const float*)d_in[0];   // (B,N,F,T)
  const float* att   = (const float*)d_in[1];   // (B,N,N)
  const float* cheb  = (const float*)d_in[2];   // (K,N,N)
  const float* theta = (const float*)d_in[3];   // (K,F,O)
  float* out = (float*)d_out;

  char* ws = (char*)d_ws;
  unsigned short* A2  = (unsigned short*)(ws);                 // 50,331,648 B
  unsigned short* xT  = (unsigned short*)(ws + 50331648);      // 12,582,912 B
  unsigned short* Y   = (unsigned short*)(ws + 62914560);      // 37,748,736 B
  unsigned short* thT = (unsigned short*)(ws + 100663296);     //     24,576 B

  k0_thetaT<<<48, 256, 0, stream>>>(theta, thT);
  k1_A2<<<dim3(16, 16), 256, 0, stream>>>(cheb, att, A2);
  k2_xT<<<dim3(64, 8), 256, 0, stream>>>(x, xT);
  k3_Y<<<dim3(4, 12, 8), 256, 0, stream>>>(xT, thT, Y);
  k4_main<<<256, 512, 0, stream>>>(A2, Y, out);
}

// Round 8
// 97.918 us; speedup vs baseline: 1.1633x; 1.1633x over previous
//
#include <hip/hip_runtime.h>
#include <stdint.h>

#define NB 8
#define NN 1024
#define NF 64
#define NT 12
#define NK 3
#define NO 64
#define NQ 768      // O*T
#define KKC 3072    // NK*NN contraction

typedef __attribute__((ext_vector_type(8))) short bf16x8;
typedef __attribute__((ext_vector_type(4))) float f32x4;

typedef const unsigned int __attribute__((address_space(1)))* gas1_t;
typedef unsigned int __attribute__((address_space(3)))* las3_t;

__device__ __forceinline__ void gload_lds16(const void* g, void* l) {
  __builtin_amdgcn_global_load_lds((gas1_t)g, (las3_t)l, 16, 0, 0);
}

__device__ __forceinline__ unsigned short f2bf(float f) {
  union { float f; unsigned int u; } v; v.f = f;
  unsigned int u = v.u;
  unsigned int r = (u + 0x7FFFu + ((u >> 16) & 1u)) >> 16;
  return (unsigned short)r;
}

// ---------------------------------------------------------------------------
// K0: thetaT[k][o][f] = bf16(theta[k][f][o])
// ---------------------------------------------------------------------------
__global__ void k0_thetaT(const float* __restrict__ theta, unsigned short* __restrict__ thT) {
  int i = blockIdx.x * 256 + threadIdx.x;
  if (i >= NK * NO * NF) return;
  int f = i & 63, o = (i >> 6) & 63, k = i >> 12;
  thT[i] = f2bf(theta[(k * NF + f) * NO + o]);
}

// ---------------------------------------------------------------------------
// K1: A2[b][n][k*1024+m] = bf16(cheb[k][m][n]*att[b][m][n])
// grid (n0,m0) = 256 blocks; cheb tiles staged once, b-loop inside.
// ---------------------------------------------------------------------------
__global__ __launch_bounds__(256) void k1_A2(const float* __restrict__ cheb,
                                             const float* __restrict__ att,
                                             unsigned short* __restrict__ A2) {
  __shared__ float att_s[64][65];
  __shared__ float cheb_s[3][64][65];
  const int n0 = blockIdx.x * 64;
  const int m0 = blockIdx.y * 64;
  const int tid = threadIdx.x;
  const int r4 = tid >> 4;
  const int c  = tid & 15;

#pragma unroll
  for (int k = 0; k < NK; ++k)
#pragma unroll
    for (int p = 0; p < 4; ++p) {
      int r = r4 + p * 16;
      const float4 v = *(const float4*)(cheb + ((size_t)(k * NN + m0 + r)) * NN + n0 + c * 4);
      cheb_s[k][r][c * 4 + 0] = v.x; cheb_s[k][r][c * 4 + 1] = v.y;
      cheb_s[k][r][c * 4 + 2] = v.z; cheb_s[k][r][c * 4 + 3] = v.w;
    }

  for (int b = 0; b < NB; ++b) {
    __syncthreads();
#pragma unroll
    for (int p = 0; p < 4; ++p) {
      int r = r4 + p * 16;
      const float4 v = *(const float4*)(att + ((size_t)(b * NN + m0 + r)) * NN + n0 + c * 4);
      att_s[r][c * 4 + 0] = v.x; att_s[r][c * 4 + 1] = v.y;
      att_s[r][c * 4 + 2] = v.z; att_s[r][c * 4 + 3] = v.w;
    }
    __syncthreads();
    for (int k = 0; k < NK; ++k) {
#pragma unroll
      for (int p = 0; p < 8; ++p) {
        int e  = p * 256 + tid;
        int jn = e >> 5;
        int q  = e & 31;
        float f0 = att_s[2 * q][jn]     * cheb_s[k][2 * q][jn];
        float f1 = att_s[2 * q + 1][jn] * cheb_s[k][2 * q + 1][jn];
        unsigned int pk = (unsigned int)f2bf(f0) | ((unsigned int)f2bf(f1) << 16);
        size_t el = ((size_t)(b * NN + n0 + jn)) * KKC + k * NN + m0 + 2 * q;
        *(unsigned int*)(A2 + el) = pk;
      }
    }
  }
}

// ---------------------------------------------------------------------------
// K23 (fused k2+k3): Y[b][(o,t)][k*1024+m] = sum_f x[b,m,f,t] * theta[k,f,o]
// Eliminates the xT intermediate (25 MB round trip + 1 launch).
// grid (mc 64, b 8) = 512 blocks, 256 thr (4 waves, 3 t's each).
// Per block: x[b, mc*16..+16, :, :] = 49 KB contiguous -> bf16 LDS t-planes
// [12][16 m][64 f] (XOR swizzle, reg-staged ds_write); thT -> LDS (b128
// swizzled, conflict-free); then per (t,k): 8 MFMA from LDS, write Y.
// ---------------------------------------------------------------------------
__global__ __launch_bounds__(256) void k23_Y(const float* __restrict__ x,
                                             const unsigned short* __restrict__ thT,
                                             unsigned short* __restrict__ Y) {
  __shared__ unsigned short Xs[12 * 16 * 64];   // 24 KB, t-plane stride 2048 B
  __shared__ unsigned short Ts[3 * 64 * 64];    // 24 KB, k-plane stride 8192 B
  const int mc = blockIdx.x;
  const int b  = blockIdx.y;
  const int tid = threadIdx.x;
  const int w = tid >> 6, l = tid & 63;
  const int lrow = l & 15, lk = l >> 4;

  // --- stage x: 512 (m,fp) units, 2/thread; each = 24 consecutive floats
  const float* xb = x + ((size_t)(b * NN + mc * 16)) * (NF * NT);
#pragma unroll
  for (int u0 = 0; u0 < 2; ++u0) {
    const int u  = u0 * 256 + tid;       // 0..511
    const int m  = u >> 5;               // 0..15
    const int fp = u & 31;               // f-pair
    const float* src = xb + ((size_t)m * NF + fp * 2) * NT;
    float v[24];
#pragma unroll
    for (int i = 0; i < 6; ++i)
      *(float4*)(v + i * 4) = *(const float4*)(src + i * 4);
#pragma unroll
    for (int t = 0; t < 12; ++t) {
      unsigned int pk = (unsigned int)f2bf(v[t]) | ((unsigned int)f2bf(v[t + 12]) << 16);
      const int byte = (t * 2048 + m * 128 + fp * 4) ^ ((m & 7) << 4);
      *(unsigned int*)((char*)Xs + byte) = pk;
    }
  }
  // --- stage thetaT: 1536 b128 units, 6/thread, swizzled (conflict-free)
#pragma unroll
  for (int u0 = 0; u0 < 6; ++u0) {
    const int u  = u0 * 256 + tid;       // 0..1535
    const int k  = u >> 9;
    const int o  = (u >> 3) & 63;
    const int f8 = u & 7;
    bf16x8 val = *(const bf16x8*)(thT + (size_t)u * 8);
    const int byte = (k * 8192 + o * 128 + f8 * 16) ^ ((o & 7) << 4);
    *(bf16x8*)((char*)Ts + byte) = val;
  }
  __syncthreads();

  // --- compute: wave w owns t in {3w, 3w+1, 3w+2}
#pragma unroll
  for (int ti = 0; ti < 3; ++ti) {
    const int t = w * 3 + ti;
    bf16x8 af[2];
#pragma unroll
    for (int kss = 0; kss < 2; ++kss) {
      const int byte = (t * 2048 + lrow * 128 + kss * 64 + lk * 16) ^ ((lrow & 7) << 4);
      af[kss] = *(const bf16x8*)((const char*)Xs + byte);
    }
    for (int k = 0; k < NK; ++k) {
      f32x4 acc[4] = {};
#pragma unroll
      for (int kss = 0; kss < 2; ++kss) {
#pragma unroll
        for (int oj = 0; oj < 4; ++oj) {
          const int row = oj * 16 + lrow;
          const int byte = (k * 8192 + row * 128 + kss * 64 + lk * 16) ^ ((row & 7) << 4);
          bf16x8 bb = *(const bf16x8*)((const char*)Ts + byte);
          acc[oj] = __builtin_amdgcn_mfma_f32_16x16x32_bf16(af[kss], bb, acc[oj], 0, 0, 0);
        }
      }
#pragma unroll
      for (int oj = 0; oj < 4; ++oj) {
        const int o  = oj * 16 + lrow;
        const int mg = mc * 16 + lk * 4;
        uint2 u;
        u.x = (unsigned int)f2bf(acc[oj][0]) | ((unsigned int)f2bf(acc[oj][1]) << 16);
        u.y = (unsigned int)f2bf(acc[oj][2]) | ((unsigned int)f2bf(acc[oj][3]) << 16);
        size_t el = ((size_t)(b * NQ + o * NT + t)) * KKC + k * NN + mg;
        *(uint2*)(void*)(Y + el) = u;
      }
    }
  }
}

// ---------------------------------------------------------------------------
// K4: out[b][n][q] = relu( A2[b] @ Y[b]^T ), 64x128 tile, BK=64 — round-3
// version (best measured): single-buffer 2-barrier, 768 blocks = 3/CU,
// XCD-chunk swizzle (96 tiles = one b per XCD), both-sides XOR swizzle.
// ---------------------------------------------------------------------------
__global__ __launch_bounds__(256) void k4_main(const unsigned short* __restrict__ A2,
                                               const unsigned short* __restrict__ Y,
                                               float* __restrict__ out) {
  __shared__ unsigned short Asl[64 * 64];    //  8 KB
  __shared__ unsigned short Bsl[128 * 64];   // 16 KB
  const int tid = threadIdx.x;
  const int w = tid >> 6, l = tid & 63;
  const int lrow = l & 15, lk = l >> 4;
  const int wm = w >> 1, wq = w & 1;

  const int lin = (blockIdx.x & 7) * 96 + (blockIdx.x >> 3);
  const int b   = lin / 96;
  const int rem = lin % 96;
  const int bn  = rem / 6;
  const int bq  = rem % 6;

  const unsigned short* Abase = A2 + ((size_t)(b * NN + bn * 64)) * KKC;
  const unsigned short* Bbase = Y  + ((size_t)(b * NQ + bq * 128)) * KKC;

  f32x4 acc[2][4] = {};

  for (int kt = 0; kt < KKC / 64; ++kt) {
    const int kb = kt * 64;
#pragma unroll
    for (int it = 0; it < 2; ++it) {
      const int idx = it * 256 + tid;
      const int r   = idx >> 3;
      const int c16 = (idx & 7) ^ (r & 7);
      gload_lds16(Abase + (size_t)r * KKC + kb + c16 * 8, Asl + (size_t)idx * 8);
    }
#pragma unroll
    for (int it = 0; it < 4; ++it) {
      const int idx = it * 256 + tid;
      const int r   = idx >> 3;
      const int c16 = (idx & 7) ^ (r & 7);
      gload_lds16(Bbase + (size_t)r * KKC + kb + c16 * 8, Bsl + (size_t)idx * 8);
    }
    __syncthreads();
#pragma unroll
    for (int kss = 0; kss < 2; ++kss) {
      bf16x8 af[2], bfr[4];
#pragma unroll
      for (int mi = 0; mi < 2; ++mi) {
        const int row = wm * 32 + mi * 16 + lrow;
        const int sw = (row * 128 + kss * 64 + lk * 16) ^ ((row & 7) << 4);
        af[mi] = *(const bf16x8*)((const char*)Asl + sw);
      }
#pragma unroll
      for (int nj = 0; nj < 4; ++nj) {
        const int row = wq * 64 + nj * 16 + lrow;
        const int sw = (row * 128 + kss * 64 + lk * 16) ^ ((row & 7) << 4);
        bfr[nj] = *(const bf16x8*)((const char*)Bsl + sw);
      }
#pragma unroll
      for (int mi = 0; mi < 2; ++mi)
#pragma unroll
        for (int nj = 0; nj < 4; ++nj)
          acc[mi][nj] = __builtin_amdgcn_mfma_f32_16x16x32_bf16(af[mi], bfr[nj], acc[mi][nj], 0, 0, 0);
    }
    __syncthreads();
  }

  const int nb0 = bn * 64 + wm * 32;
  const int qb0 = bq * 128 + wq * 64;
#pragma unroll
  for (int mi = 0; mi < 2; ++mi) {
#pragma unroll
    for (int nj = 0; nj < 4; ++nj) {
      const int q = qb0 + nj * 16 + lrow;
#pragma unroll
      for (int j = 0; j < 4; ++j) {
        const int n = nb0 + mi * 16 + lk * 4 + j;
        float v = acc[mi][nj][j];
        out[((size_t)(b * NN + n)) * NQ + q] = v > 0.f ? v : 0.f;
      }
    }
  }
}

// ---------------------------------------------------------------------------
extern "C" void kernel_launch(void* const* d_in, const int* in_sizes, int n_in,
                              void* d_out, int out_size, void* d_ws, size_t ws_size,
                              hipStream_t stream) {
  const float* x     = (const float*)d_in[0];   // (B,N,F,T)
  const float* att   = (const float*)d_in[1];   // (B,N,N)
  const float* cheb  = (const float*)d_in[2];   // (K,N,N)
  const float* theta = (const float*)d_in[3];   // (K,F,O)
  float* out = (float*)d_out;

  char* ws = (char*)d_ws;
  unsigned short* A2  = (unsigned short*)(ws);                 // 50,331,648 B
  unsigned short* Y   = (unsigned short*)(ws + 50331648);      // 37,748,736 B
  unsigned short* thT = (unsigned short*)(ws + 88080384);      //     24,576 B

  k0_thetaT<<<48, 256, 0, stream>>>(theta, thT);
  k23_Y<<<dim3(64, 8), 256, 0, stream>>>(x, thT, Y);
  k1_A2<<<dim3(16, 16), 256, 0, stream>>>(cheb, att, A2);
  k4_main<<<768, 256, 0, stream>>>(A2, Y, out);
}

// Round 9
// 96.298 us; speedup vs baseline: 1.1829x; 1.0168x over previous
//
#include <hip/hip_runtime.h>
#include <stdint.h>

#define NB 8
#define NN 1024
#define NF 64
#define NT 12
#define NK 3
#define NO 64
#define NQ 768      // O*T
#define KKC 3072    // NK*NN contraction

typedef __attribute__((ext_vector_type(8))) short bf16x8;
typedef __attribute__((ext_vector_type(4))) float f32x4;

typedef const unsigned int __attribute__((address_space(1)))* gas1_t;
typedef unsigned int __attribute__((address_space(3)))* las3_t;

__device__ __forceinline__ void gload_lds16(const void* g, void* l) {
  __builtin_amdgcn_global_load_lds((gas1_t)g, (las3_t)l, 16, 0, 0);
}

__device__ __forceinline__ unsigned short f2bf(float f) {
  union { float f; unsigned int u; } v; v.f = f;
  unsigned int u = v.u;
  unsigned int r = (u + 0x7FFFu + ((u >> 16) & 1u)) >> 16;
  return (unsigned short)r;
}

// ---------------------------------------------------------------------------
// K0: thetaT[k][o][f] = bf16(theta[k][f][o])
// ---------------------------------------------------------------------------
__global__ void k0_thetaT(const float* __restrict__ theta, unsigned short* __restrict__ thT) {
  int i = blockIdx.x * 256 + threadIdx.x;
  if (i >= NK * NO * NF) return;
  int f = i & 63, o = (i >> 6) & 63, k = i >> 12;
  thT[i] = f2bf(theta[(k * NF + f) * NO + o]);
}

// ---------------------------------------------------------------------------
// K1: A2[b][n][k*1024+m] = bf16(cheb[k][m][n]*att[b][m][n])
// grid (n0,m0) = 256 blocks; cheb tiles staged once, b-loop inside.
// ---------------------------------------------------------------------------
__global__ __launch_bounds__(256) void k1_A2(const float* __restrict__ cheb,
                                             const float* __restrict__ att,
                                             unsigned short* __restrict__ A2) {
  __shared__ float att_s[64][65];
  __shared__ float cheb_s[3][64][65];
  const int n0 = blockIdx.x * 64;
  const int m0 = blockIdx.y * 64;
  const int tid = threadIdx.x;
  const int r4 = tid >> 4;
  const int c  = tid & 15;

#pragma unroll
  for (int k = 0; k < NK; ++k)
#pragma unroll
    for (int p = 0; p < 4; ++p) {
      int r = r4 + p * 16;
      const float4 v = *(const float4*)(cheb + ((size_t)(k * NN + m0 + r)) * NN + n0 + c * 4);
      cheb_s[k][r][c * 4 + 0] = v.x; cheb_s[k][r][c * 4 + 1] = v.y;
      cheb_s[k][r][c * 4 + 2] = v.z; cheb_s[k][r][c * 4 + 3] = v.w;
    }

  for (int b = 0; b < NB; ++b) {
    __syncthreads();
#pragma unroll
    for (int p = 0; p < 4; ++p) {
      int r = r4 + p * 16;
      const float4 v = *(const float4*)(att + ((size_t)(b * NN + m0 + r)) * NN + n0 + c * 4);
      att_s[r][c * 4 + 0] = v.x; att_s[r][c * 4 + 1] = v.y;
      att_s[r][c * 4 + 2] = v.z; att_s[r][c * 4 + 3] = v.w;
    }
    __syncthreads();
    for (int k = 0; k < NK; ++k) {
#pragma unroll
      for (int p = 0; p < 8; ++p) {
        int e  = p * 256 + tid;
        int jn = e >> 5;
        int q  = e & 31;
        float f0 = att_s[2 * q][jn]     * cheb_s[k][2 * q][jn];
        float f1 = att_s[2 * q + 1][jn] * cheb_s[k][2 * q + 1][jn];
        unsigned int pk = (unsigned int)f2bf(f0) | ((unsigned int)f2bf(f1) << 16);
        size_t el = ((size_t)(b * NN + n0 + jn)) * KKC + k * NN + m0 + 2 * q;
        *(unsigned int*)(A2 + el) = pk;
      }
    }
  }
}

// ---------------------------------------------------------------------------
// K23 (fused k2+k3): Y[b][(o,t)][k*1024+m] = sum_f x[b,m,f,t] * theta[k,f,o]
// grid (mc 64, b 8) = 512 blocks, 256 thr (4 waves, 3 t's each).
// ---------------------------------------------------------------------------
__global__ __launch_bounds__(256) void k23_Y(const float* __restrict__ x,
                                             const unsigned short* __restrict__ thT,
                                             unsigned short* __restrict__ Y) {
  __shared__ unsigned short Xs[12 * 16 * 64];   // 24 KB, t-plane stride 2048 B
  __shared__ unsigned short Ts[3 * 64 * 64];    // 24 KB, k-plane stride 8192 B
  const int mc = blockIdx.x;
  const int b  = blockIdx.y;
  const int tid = threadIdx.x;
  const int w = tid >> 6, l = tid & 63;
  const int lrow = l & 15, lk = l >> 4;

  const float* xb = x + ((size_t)(b * NN + mc * 16)) * (NF * NT);
#pragma unroll
  for (int u0 = 0; u0 < 2; ++u0) {
    const int u  = u0 * 256 + tid;       // 0..511
    const int m  = u >> 5;               // 0..15
    const int fp = u & 31;               // f-pair
    const float* src = xb + ((size_t)m * NF + fp * 2) * NT;
    float v[24];
#pragma unroll
    for (int i = 0; i < 6; ++i)
      *(float4*)(v + i * 4) = *(const float4*)(src + i * 4);
#pragma unroll
    for (int t = 0; t < 12; ++t) {
      unsigned int pk = (unsigned int)f2bf(v[t]) | ((unsigned int)f2bf(v[t + 12]) << 16);
      const int byte = (t * 2048 + m * 128 + fp * 4) ^ ((m & 7) << 4);
      *(unsigned int*)((char*)Xs + byte) = pk;
    }
  }
#pragma unroll
  for (int u0 = 0; u0 < 6; ++u0) {
    const int u  = u0 * 256 + tid;       // 0..1535
    const int k  = u >> 9;
    const int o  = (u >> 3) & 63;
    const int f8 = u & 7;
    bf16x8 val = *(const bf16x8*)(thT + (size_t)u * 8);
    const int byte = (k * 8192 + o * 128 + f8 * 16) ^ ((o & 7) << 4);
    *(bf16x8*)((char*)Ts + byte) = val;
  }
  __syncthreads();

#pragma unroll
  for (int ti = 0; ti < 3; ++ti) {
    const int t = w * 3 + ti;
    bf16x8 af[2];
#pragma unroll
    for (int kss = 0; kss < 2; ++kss) {
      const int byte = (t * 2048 + lrow * 128 + kss * 64 + lk * 16) ^ ((lrow & 7) << 4);
      af[kss] = *(const bf16x8*)((const char*)Xs + byte);
    }
    for (int k = 0; k < NK; ++k) {
      f32x4 acc[4] = {};
#pragma unroll
      for (int kss = 0; kss < 2; ++kss) {
#pragma unroll
        for (int oj = 0; oj < 4; ++oj) {
          const int row = oj * 16 + lrow;
          const int byte = (k * 8192 + row * 128 + kss * 64 + lk * 16) ^ ((row & 7) << 4);
          bf16x8 bb = *(const bf16x8*)((const char*)Ts + byte);
          acc[oj] = __builtin_amdgcn_mfma_f32_16x16x32_bf16(af[kss], bb, acc[oj], 0, 0, 0);
        }
      }
#pragma unroll
      for (int oj = 0; oj < 4; ++oj) {
        const int o  = oj * 16 + lrow;
        const int mg = mc * 16 + lk * 4;
        uint2 u;
        u.x = (unsigned int)f2bf(acc[oj][0]) | ((unsigned int)f2bf(acc[oj][1]) << 16);
        u.y = (unsigned int)f2bf(acc[oj][2]) | ((unsigned int)f2bf(acc[oj][3]) << 16);
        size_t el = ((size_t)(b * NQ + o * NT + t)) * KKC + k * NN + mg;
        *(uint2*)(void*)(Y + el) = u;
      }
    }
  }
}

// ---------------------------------------------------------------------------
// K4: out[b][n][q] = relu( A2[b] @ Y[b]^T ), 128x96 tile, BK=64.
// Grid 8x8x8 = 512 blocks = exactly 2/CU: 22% fewer staged bytes (704 MB)
// than the 64x128/768-block config, while keeping 2 independent blocks/CU
// for cross-block overlap (r7 showed 1 block/CU collapses delivery).
// Per wave 64x48 (acc 4x3, 24 MFMA/K-step). Single-buffer 2-barrier (r3
// structure). XCD chunk = 64 blocks = one b.
// ---------------------------------------------------------------------------
__global__ __launch_bounds__(256) void k4_main(const unsigned short* __restrict__ A2,
                                               const unsigned short* __restrict__ Y,
                                               float* __restrict__ out) {
  __shared__ unsigned short Asl[128 * 64];   // 16 KB
  __shared__ unsigned short Bsl[96 * 64];    // 12 KB
  const int tid = threadIdx.x;
  const int w = tid >> 6, l = tid & 63;
  const int lrow = l & 15, lk = l >> 4;
  const int wm = w >> 1, wq = w & 1;

  // bijective XCD-chunk swizzle (512 % 8 == 0); 64 blocks = one b per XCD
  const int lin = (blockIdx.x & 7) * 64 + (blockIdx.x >> 3);
  const int b   = lin >> 6;
  const int rem = lin & 63;
  const int bn  = rem >> 3;      // 0..7, 128-row n-tile
  const int bq  = rem & 7;       // 0..7, 96-col q-tile

  const unsigned short* Abase = A2 + ((size_t)(b * NN + bn * 128)) * KKC;
  const unsigned short* Bbase = Y  + ((size_t)(b * NQ + bq * 96)) * KKC;

  f32x4 acc[4][3] = {};

  for (int kt = 0; kt < KKC / 64; ++kt) {
    const int kb = kt * 64;
    // stage A: 128 rows x 8 units = 1024 units, 4/thread
#pragma unroll
    for (int it = 0; it < 4; ++it) {
      const int idx = it * 256 + tid;
      const int r   = idx >> 3;
      const int c16 = (idx & 7) ^ (r & 7);
      gload_lds16(Abase + (size_t)r * KKC + kb + c16 * 8, Asl + (size_t)idx * 8);
    }
    // stage B: 96 rows x 8 units = 768 units, 3/thread
#pragma unroll
    for (int it = 0; it < 3; ++it) {
      const int idx = it * 256 + tid;
      const int r   = idx >> 3;
      const int c16 = (idx & 7) ^ (r & 7);
      gload_lds16(Bbase + (size_t)r * KKC + kb + c16 * 8, Bsl + (size_t)idx * 8);
    }
    __syncthreads();
#pragma unroll
    for (int kss = 0; kss < 2; ++kss) {
      bf16x8 af[4], bfr[3];
#pragma unroll
      for (int mi = 0; mi < 4; ++mi) {
        const int row = wm * 64 + mi * 16 + lrow;
        const int sw = (row * 128 + kss * 64 + lk * 16) ^ ((row & 7) << 4);
        af[mi] = *(const bf16x8*)((const char*)Asl + sw);
      }
#pragma unroll
      for (int nj = 0; nj < 3; ++nj) {
        const int row = wq * 48 + nj * 16 + lrow;
        const int sw = (row * 128 + kss * 64 + lk * 16) ^ ((row & 7) << 4);
        bfr[nj] = *(const bf16x8*)((const char*)Bsl + sw);
      }
#pragma unroll
      for (int mi = 0; mi < 4; ++mi)
#pragma unroll
        for (int nj = 0; nj < 3; ++nj)
          acc[mi][nj] = __builtin_amdgcn_mfma_f32_16x16x32_bf16(af[mi], bfr[nj], acc[mi][nj], 0, 0, 0);
    }
    __syncthreads();
  }

  const int nb0 = bn * 128 + wm * 64;
  const int qb0 = bq * 96 + wq * 48;
#pragma unroll
  for (int mi = 0; mi < 4; ++mi) {
#pragma unroll
    for (int nj = 0; nj < 3; ++nj) {
      const int q = qb0 + nj * 16 + lrow;
#pragma unroll
      for (int j = 0; j < 4; ++j) {
        const int n = nb0 + mi * 16 + lk * 4 + j;
        float v = acc[mi][nj][j];
        out[((size_t)(b * NN + n)) * NQ + q] = v > 0.f ? v : 0.f;
      }
    }
  }
}

// ---------------------------------------------------------------------------
extern "C" void kernel_launch(void* const* d_in, const int* in_sizes, int n_in,
                              void* d_out, int out_size, void* d_ws, size_t ws_size,
                              hipStream_t stream) {
  const float* x     = (const float*)d_in[0];   // (B,N,F,T)
  const float* att   = (const float*)d_in[1];   // (B,N,N)
  const float* cheb  = (const float*)d_in[2];   // (K,N,N)
  const float* theta = (const float*)d_in[3];   // (K,F,O)
  float* out = (float*)d_out;

  char* ws = (char*)d_ws;
  unsigned short* A2  = (unsigned short*)(ws);                 // 50,331,648 B
  unsigned short* Y   = (unsigned short*)(ws + 50331648);      // 37,748,736 B
  unsigned short* thT = (unsigned short*)(ws + 88080384);      //     24,576 B

  k0_thetaT<<<48, 256, 0, stream>>>(theta, thT);
  k23_Y<<<dim3(64, 8), 256, 0, stream>>>(x, thT, Y);
  k1_A2<<<dim3(16, 16), 256, 0, stream>>>(cheb, att, A2);
  k4_main<<<512, 256, 0, stream>>>(A2, Y, out);
}